// Round 1
// baseline (370.269 us; speedup 1.0000x reference)
//
#include <hip/hip_runtime.h>

// Shapes (fixed): B=4, NH=8, DIM=32, WS=8, WA=64, H=W=128, planes 128*128=16384.
// qkv:  (4, 8, 96, 128, 128) f32      ch: (4, 256, 128, 128) f32
// lsc:  (8) f32   btab: (225, 8) f32  pw: (256,256) f32  pb: (256) f32
// ridx: (64,64) i32                   out: (4, 256, 128, 128) f32

__global__ __launch_bounds__(256) void attn_kernel(
    const float* __restrict__ qkv, const float* __restrict__ ch,
    const float* __restrict__ lsc, const float* __restrict__ btab,
    const int* __restrict__ ridx, float* __restrict__ out)
{
  __shared__ float chm[64][36];
  __shared__ float qs[64][36];
  __shared__ float ks[64][36];   // doubles as output staging after PV
  __shared__ float vs[64][36];
  __shared__ float att[64][68];
  __shared__ float inq[64], ink[64];

  const int tid = threadIdx.x;
  const int wid = blockIdx.x;            // 1024 = 4 b * 16 wy * 16 wx
  const int b  = wid >> 8;
  const int wy = (wid >> 4) & 15, wx = wid & 15;
  const int y0 = wy << 3, x0 = wx << 3;

  // chm[p][c] = mean over 8 helper layers of ch[b][l*32+c][y][x]
  for (int i = tid; i < 2048; i += 256) {
    const int c = i >> 6, p = i & 63;
    const float* src = ch + (((size_t)(b << 8) + c) << 14)
                     + ((y0 + (p >> 3)) << 7) + (x0 + (p & 7));
    float s = 0.f;
#pragma unroll
    for (int l = 0; l < 8; ++l) s += src[(size_t)(l << 5) << 14];
    chm[p][c] = s * 0.125f;
  }
  __syncthreads();

  for (int h = 0; h < 8; ++h) {
    const float scale = __expf(fminf(lsc[h], 4.6051701859880914f)); // min(ls, log(100))
    const float* qb = qkv + (((size_t)((b << 3) + h) * 96) << 14);

    // stage q, k, v*chm into LDS
    for (int i = tid; i < 2048; i += 256) {
      const int c = i >> 6, p = i & 63;
      const int sp = ((y0 + (p >> 3)) << 7) + (x0 + (p & 7));
      qs[p][c] = qb[((size_t)c << 14) + sp];
      ks[p][c] = qb[((size_t)(c + 32) << 14) + sp];
      vs[p][c] = qb[((size_t)(c + 64) << 14) + sp] * chm[p][c];
    }
    __syncthreads();

    // l2-norm factors (scale folded into inq)
    if (tid < 64) {
      float sq = 0.f, sk = 0.f;
#pragma unroll
      for (int c = 0; c < 32; ++c) {
        sq = fmaf(qs[tid][c], qs[tid][c], sq);
        sk = fmaf(ks[tid][c], ks[tid][c], sk);
      }
      inq[tid] = scale / fmaxf(sqrtf(sq), 1e-12f);
      ink[tid] = 1.f   / fmaxf(sqrtf(sk), 1e-12f);
    }
    __syncthreads();

    // QK^T, 4x4 register tile per thread; j-tiles interleaved (stride 16)
    {
      const int it = tid >> 4, jt = tid & 15;
      const int i0 = it << 2;
      float acc[4][4];
#pragma unroll
      for (int a = 0; a < 4; ++a)
#pragma unroll
        for (int bb = 0; bb < 4; ++bb) acc[a][bb] = 0.f;
#pragma unroll
      for (int c = 0; c < 32; ++c) {
        float qr[4], kr[4];
#pragma unroll
        for (int a = 0; a < 4; ++a) qr[a] = qs[i0 + a][c];
#pragma unroll
        for (int bb = 0; bb < 4; ++bb) kr[bb] = ks[jt + (bb << 4)][c];
#pragma unroll
        for (int a = 0; a < 4; ++a)
#pragma unroll
          for (int bb = 0; bb < 4; ++bb) acc[a][bb] = fmaf(qr[a], kr[bb], acc[a][bb]);
      }
#pragma unroll
      for (int a = 0; a < 4; ++a) {
        const int i = i0 + a;
        const float fi = inq[i];
#pragma unroll
        for (int bb = 0; bb < 4; ++bb) {
          const int j = jt + (bb << 4);
          att[i][j] = fi * ink[j] * acc[a][bb]
                    + btab[(ridx[(i << 6) + j] << 3) + h];
        }
      }
    }
    __syncthreads();

    // softmax: row i = tid>>2, 4 threads per row, j interleaved stride 4
    {
      const int i = tid >> 2, g = tid & 3;
      float e[16], m = -1e30f;
#pragma unroll
      for (int jj = 0; jj < 16; ++jj) { e[jj] = att[i][g + (jj << 2)]; m = fmaxf(m, e[jj]); }
      m = fmaxf(m, __shfl_xor(m, 1));
      m = fmaxf(m, __shfl_xor(m, 2));
      float s = 0.f;
#pragma unroll
      for (int jj = 0; jj < 16; ++jj) { e[jj] = __expf(e[jj] - m); s += e[jj]; }
      s += __shfl_xor(s, 1);
      s += __shfl_xor(s, 2);
      const float rs = 1.f / s;
#pragma unroll
      for (int jj = 0; jj < 16; ++jj) att[i][g + (jj << 2)] = e[jj] * rs;
    }
    __syncthreads();

    // PV: 4p x 2c register tile per thread (c interleaved stride 16)
    {
      const int p0 = (tid >> 4) << 2, ct = tid & 15;
      float a0[4], a1[4];
#pragma unroll
      for (int a = 0; a < 4; ++a) { a0[a] = 0.f; a1[a] = 0.f; }
#pragma unroll 4
      for (int j = 0; j < 64; ++j) {
        const float v0 = vs[j][ct], v1 = vs[j][ct + 16];
#pragma unroll
        for (int a = 0; a < 4; ++a) {
          const float w_ = att[p0 + a][j];
          a0[a] = fmaf(w_, v0, a0[a]);
          a1[a] = fmaf(w_, v1, a1[a]);
        }
      }
      __syncthreads();             // all PV reads of ks-era data done (none) / att,vs done
#pragma unroll
      for (int a = 0; a < 4; ++a) { ks[p0 + a][ct] = a0[a]; ks[p0 + a][ct + 16] = a1[a]; }
    }
    __syncthreads();

    // coalesced-ish store: out[b][h*32+c][y][x]
    {
      const size_t ob = ((size_t)(b << 8) + (h << 5)) << 14;
      for (int i = tid; i < 2048; i += 256) {
        const int c = i >> 6, p = i & 63;
        out[ob + ((size_t)c << 14) + ((y0 + (p >> 3)) << 7) + (x0 + (p & 7))] = ks[p][c];
      }
    }
    __syncthreads();
  }
}

// In-place 1x1-conv projection on d_out: each block owns 64 consecutive
// positions of one batch image across all 256 channels. All global reads of
// x for those positions complete (LDS-staged + syncthreads) before any write.
__global__ __launch_bounds__(256) void proj_kernel(
    float* __restrict__ x, const float* __restrict__ w, const float* __restrict__ bias)
{
  __shared__ float xt[16][64];
  __shared__ float wt[16][260];   // transposed w chunk, padded
  const int tid = threadIdx.x;
  const int blk = blockIdx.x;     // 1024 = 4 b * 256 position-blocks
  const int b = blk >> 8;
  const int P0 = (blk & 255) << 6;
  const int to = tid & 31, tp = tid >> 5;
  const int o0 = to << 3, p0 = tp << 3;
  float acc[8][8];
#pragma unroll
  for (int a = 0; a < 8; ++a)
#pragma unroll
    for (int c = 0; c < 8; ++c) acc[a][c] = 0.f;

  float* xb = x + (((size_t)b << 8) << 14) + P0;

  for (int cb = 0; cb < 16; ++cb) {
    for (int i = tid; i < 1024; i += 256) {
      const int cc = i >> 6, p = i & 63;
      xt[cc][p] = xb[((size_t)(cb * 16 + cc) << 14) + p];
    }
    for (int i = tid; i < 4096; i += 256) {
      const int o = i >> 4, c = i & 15;
      wt[c][o] = w[(o << 8) + cb * 16 + c];
    }
    __syncthreads();
#pragma unroll
    for (int cc = 0; cc < 16; ++cc) {
      float xr[8], wr[8];
#pragma unroll
      for (int ip = 0; ip < 8; ++ip) xr[ip] = xt[cc][p0 + ip];
#pragma unroll
      for (int io = 0; io < 8; ++io) wr[io] = wt[cc][o0 + io];
#pragma unroll
      for (int io = 0; io < 8; ++io)
#pragma unroll
        for (int ip = 0; ip < 8; ++ip) acc[io][ip] = fmaf(wr[io], xr[ip], acc[io][ip]);
    }
    __syncthreads();
  }

#pragma unroll
  for (int io = 0; io < 8; ++io) {
    const float bv = bias[o0 + io];
#pragma unroll
    for (int ip = 0; ip < 8; ++ip)
      xb[((size_t)(o0 + io) << 14) + p0 + ip] = acc[io][ip] + bv;
  }
}

extern "C" void kernel_launch(void* const* d_in, const int* in_sizes, int n_in,
                              void* d_out, int out_size, void* d_ws, size_t ws_size,
                              hipStream_t stream) {
  const float* qkv  = (const float*)d_in[0];
  const float* ch   = (const float*)d_in[1];
  const float* lsc  = (const float*)d_in[2];
  const float* btab = (const float*)d_in[3];
  const float* pw   = (const float*)d_in[4];
  const float* pb   = (const float*)d_in[5];
  const int*   ridx = (const int*)d_in[6];
  float* out = (float*)d_out;

  attn_kernel<<<dim3(1024), dim3(256), 0, stream>>>(qkv, ch, lsc, btab, ridx, out);
  proj_kernel<<<dim3(1024), dim3(256), 0, stream>>>(out, pw, pb);
}

// Round 2
// 143.469 us; speedup vs baseline: 2.5808x; 2.5808x over previous
//
#include <hip/hip_runtime.h>

// Shapes: B=4, NH=8, DIM=32, WS=8, WA=64, H=W=128, PLANE=16384.
// qkv:(4,8,96,128,128)f32  ch:(4,256,128,128)f32  lsc:(8)  btab:(225,8)
// pw:(256,256)  pb:(256)  ridx:(64,64)i32  out:(4,256,128,128)f32
//
// ws layout: xtmp bf16 [4*16384][256]  @0        (32 MB)
//            chm  f32  [4][32][16384]  @32M      (8 MB)
//            biasG f32 [8][64][64]     @40M      (128 KB)
//            wbf  bf16 [256][256]      @40M+128K (128 KB)

typedef __attribute__((ext_vector_type(8))) short short8v;
typedef __attribute__((ext_vector_type(4))) float f32x4;
typedef __attribute__((ext_vector_type(2))) unsigned int u32x2;

#define PLANE 16384
#define LSTR  133   // f32 LDS row stride for Q/K ([32][133])

static __device__ __forceinline__ unsigned short f2bf(float x) {
  union { float f; unsigned u; } v; v.f = x;
  unsigned r = v.u + 0x7fff + ((v.u >> 16) & 1);
  return (unsigned short)(r >> 16);
}
static __device__ __forceinline__ float bf2f(unsigned short b) {
  union { unsigned u; float f; } v; v.u = ((unsigned)b) << 16;
  return v.f;
}

__global__ __launch_bounds__(256) void prep_kernel(
    const float* __restrict__ ch, const float* __restrict__ btab,
    const int* __restrict__ ridx, const float* __restrict__ pw,
    float* __restrict__ chm, float* __restrict__ biasG,
    unsigned int* __restrict__ wbf)
{
  const int blk = blockIdx.x, tid = threadIdx.x;
  if (blk < 8192) {                       // chm: mean over 8 helper layers
    int idx = blk * 256 + tid;            // [0, 2M)
    int b = idx >> 19, c = (idx >> 14) & 31, p = idx & 16383;
    const float* src = ch + ((size_t)(b * 256 + c)) * PLANE + p;
    float s = 0.f;
#pragma unroll
    for (int l = 0; l < 8; ++l) s += src[(size_t)(l * 32) * PLANE];
    chm[((size_t)(b * 32 + c)) * PLANE + p] = s * 0.125f;
  } else if (blk < 8320) {                // biasG[h][q][k]
    int i = (blk - 8192) * 256 + tid;     // [0, 32768)
    int h = i >> 12, qk = i & 4095;
    biasG[i] = btab[ridx[qk] * 8 + h];
  } else {                                // w -> bf16 (packed pairs)
    int i = (blk - 8320) * 256 + tid;     // [0, 32768)
    float a = pw[i * 2], b2 = pw[i * 2 + 1];
    wbf[i] = (unsigned)f2bf(a) | ((unsigned)f2bf(b2) << 16);
  }
}

// block = (window-pair, head): 512 pairs * 8 heads = 4096 blocks, 256 thr.
__global__ __launch_bounds__(256) void attn_kernel(
    const float* __restrict__ qkv, const float* __restrict__ chm,
    const float* __restrict__ lsc, const float* __restrict__ biasG,
    unsigned short* __restrict__ xtmp)
{
  __shared__ float Qs[32 * LSTR];
  __shared__ float Ks[32 * LSTR];
  __shared__ __align__(16) float nq[128];   // idx = win*64 + pos (scale/||q||)
  __shared__ __align__(16) float nk[128];   // 1/||k||

  const int tid = threadIdx.x;
  const int bw  = blockIdx.x;
  const int h   = bw & 7;
  const int pi  = bw >> 3;                 // pair index 0..511
  const int b   = pi >> 7;
  const int wy  = (pi >> 3) & 15;
  const int wxp = pi & 7;
  const int y0  = wy << 3, x0 = wxp << 4;

  const size_t qbase = ((size_t)((b * 8 + h) * 96)) * PLANE;
  const float* qg = qkv + qbase;
  const float* kg = qkv + qbase + (size_t)32 * PLANE;
  const float* vg = qkv + qbase + (size_t)64 * PLANE;
  const float* cg = chm + (size_t)(b * 32) * PLANE;

  // ---- stage Q, K (f32) into LDS [d][p_pair], p_pair = y*16 + x16
  for (int i = tid; i < 4096; i += 256) {
    int d = i >> 7, p = i & 127;
    int sp = (y0 + (p >> 4)) * 128 + x0 + (p & 15);
    Qs[d * LSTR + p] = qg[(size_t)d * PLANE + sp];
    Ks[d * LSTR + p] = kg[(size_t)d * PLANE + sp];
  }
  __syncthreads();

  // ---- per-position l2 norms (f32, exact); fold logit scale into q-side
  {
    float scale = __expf(fminf(lsc[h], 4.6051701859880914f));
    int p = tid & 127;
    const float* M = (tid < 128) ? Qs : Ks;
    float s = 0.f;
#pragma unroll
    for (int d = 0; d < 32; ++d) { float x = M[d * LSTR + p]; s = fmaf(x, x, s); }
    float inv = 1.f / fmaxf(sqrtf(s), 1e-12f);
    int win = (p >> 3) & 1, pos = ((p >> 4) << 3) + (p & 7);
    if (tid < 128) nq[win * 64 + pos] = inv * scale;
    else           nk[win * 64 + pos] = inv;
  }
  __syncthreads();

  const int wv = tid >> 6, lane = tid & 63;
  const int win = wv >> 1, sub = wv & 1;
  const int lg = lane >> 4, lr = lane & 15;
  const int xw = x0 + win * 8;

  // ---- K A-frags (hi/lo bf16 split), kt tile: kpos = 16*kt + lr, d = 8*lg+j
  short8v khi[4], klo[4];
#pragma unroll
  for (int kt = 0; kt < 4; ++kt) {
    int kpos = 16 * kt + lr;
    int pp = ((kpos >> 3) << 4) + win * 8 + (kpos & 7);
#pragma unroll
    for (int j = 0; j < 8; ++j) {
      float x = Ks[(8 * lg + j) * LSTR + pp];
      unsigned short hb = f2bf(x);
      khi[kt][j] = (short)hb;
      klo[kt][j] = (short)f2bf(x - bf2f(hb));
    }
  }

  // ---- V*chm A-frags, sigma-permuted: elem j <- kpos 4*lg+(j&3)+16*(j>>2)+32*m
  short8v vf[2][2];
#pragma unroll
  for (int dt = 0; dt < 2; ++dt) {
    int d = 16 * dt + lr;
    const float* vp = vg + (size_t)d * PLANE;
    const float* cp = cg + (size_t)d * PLANE;
#pragma unroll
    for (int m = 0; m < 2; ++m) {
      int ka = 4 * lg + 32 * m, kb = ka + 16;
      int spa = (y0 + (ka >> 3)) * 128 + xw + (ka & 7);
      int spb = (y0 + (kb >> 3)) * 128 + xw + (kb & 7);
      float4 va = *(const float4*)(vp + spa);
      float4 ca = *(const float4*)(cp + spa);
      float4 vb = *(const float4*)(vp + spb);
      float4 cb = *(const float4*)(cp + spb);
      vf[dt][m][0] = (short)f2bf(va.x * ca.x);
      vf[dt][m][1] = (short)f2bf(va.y * ca.y);
      vf[dt][m][2] = (short)f2bf(va.z * ca.z);
      vf[dt][m][3] = (short)f2bf(va.w * ca.w);
      vf[dt][m][4] = (short)f2bf(vb.x * cb.x);
      vf[dt][m][5] = (short)f2bf(vb.y * cb.y);
      vf[dt][m][6] = (short)f2bf(vb.z * cb.z);
      vf[dt][m][7] = (short)f2bf(vb.w * cb.w);
    }
  }

  // ---- two q-strips of 16 per wave
#pragma unroll
  for (int si = 0; si < 2; ++si) {
    int st = 2 * sub + si;
    int q = 16 * st + lr;
    int pq = ((q >> 3) << 4) + win * 8 + (q & 7);

    short8v qhi, qlo;
#pragma unroll
    for (int j = 0; j < 8; ++j) {
      float x = Qs[(8 * lg + j) * LSTR + pq];
      unsigned short hb = f2bf(x);
      qhi[j] = (short)hb;
      qlo[j] = (short)f2bf(x - bf2f(hb));
    }

    // S^T tiles: D[r=kpos-in-tile][c=q], split-precision 3-MFMA
    f32x4 acc[4];
#pragma unroll
    for (int kt = 0; kt < 4; ++kt) {
      f32x4 a = {0.f, 0.f, 0.f, 0.f};
      a = __builtin_amdgcn_mfma_f32_16x16x32_bf16(klo[kt], qhi, a, 0, 0, 0);
      a = __builtin_amdgcn_mfma_f32_16x16x32_bf16(khi[kt], qlo, a, 0, 0, 0);
      a = __builtin_amdgcn_mfma_f32_16x16x32_bf16(khi[kt], qhi, a, 0, 0, 0);
      acc[kt] = a;
    }

    // logits + lane-local softmax (kpos = 16*kt + 4*lg + r)
    float fq = nq[win * 64 + q];
    const float4* bq = (const float4*)(biasG + ((h * 64 + q) << 6));
    float e[16], mx = -1e30f;
#pragma unroll
    for (int kt = 0; kt < 4; ++kt) {
      float4 b4 = bq[4 * kt + lg];
      float bb[4] = {b4.x, b4.y, b4.z, b4.w};
      f32x4 fk4 = *(const f32x4*)(&nk[win * 64 + 16 * kt + 4 * lg]);
#pragma unroll
      for (int r = 0; r < 4; ++r) {
        float lv = acc[kt][r] * (fq * fk4[r]) + bb[r];
        e[4 * kt + r] = lv;
        mx = fmaxf(mx, lv);
      }
    }
    mx = fmaxf(mx, __shfl_xor(mx, 16));
    mx = fmaxf(mx, __shfl_xor(mx, 32));
    float s = 0.f;
#pragma unroll
    for (int i = 0; i < 16; ++i) { e[i] = __expf(e[i] - mx); s += e[i]; }
    s += __shfl_xor(s, 16);
    s += __shfl_xor(s, 32);
    float rl = 1.f / s;

    // P B-frags, same sigma permutation: pf[m][j] = e[4*(j>>2) + 8*m + (j&3)]
    short8v pf[2];
#pragma unroll
    for (int m = 0; m < 2; ++m)
#pragma unroll
      for (int j = 0; j < 8; ++j)
        pf[m][j] = (short)f2bf(e[4 * (j >> 2) + 8 * m + (j & 3)]);

    // PV: D[r=d-in-tile][c=q]; store bf16 to xtmp position-major
    int pg = (y0 + (q >> 3)) * 128 + xw + (q & 7);
#pragma unroll
    for (int dt = 0; dt < 2; ++dt) {
      f32x4 o = {0.f, 0.f, 0.f, 0.f};
      o = __builtin_amdgcn_mfma_f32_16x16x32_bf16(vf[dt][0], pf[0], o, 0, 0, 0);
      o = __builtin_amdgcn_mfma_f32_16x16x32_bf16(vf[dt][1], pf[1], o, 0, 0, 0);
      size_t base = ((size_t)(b * PLANE + pg)) * 256 + h * 32 + 16 * dt + 4 * lg;
      u32x2 ww;
      ww[0] = (unsigned)f2bf(o[0] * rl) | ((unsigned)f2bf(o[1] * rl) << 16);
      ww[1] = (unsigned)f2bf(o[2] * rl) | ((unsigned)f2bf(o[3] * rl) << 16);
      *(u32x2*)(xtmp + base) = ww;
    }
  }
}

// GEMM out[o][p] = sum_c w[o][c] * x[p][c] + pb[o]; no LDS, frags from L2/L3.
__global__ __launch_bounds__(256) void proj_kernel(
    const unsigned short* __restrict__ xtmp, const unsigned short* __restrict__ wbf,
    const float* __restrict__ pb, float* __restrict__ out)
{
  const int tid = threadIdx.x, lane = tid & 63, wv = tid >> 6;
  const int lg = lane >> 4, lr = lane & 15;
  const int P0 = blockIdx.x * 64;    // 64 consecutive positions (one batch)
  const int o0 = wv * 64;

  f32x4 acc[4][4];
#pragma unroll
  for (int i = 0; i < 4; ++i)
#pragma unroll
    for (int j = 0; j < 4; ++j) acc[i][j] = (f32x4){0.f, 0.f, 0.f, 0.f};

#pragma unroll
  for (int kc = 0; kc < 8; ++kc) {
    short8v wf[4], xf[4];
#pragma unroll
    for (int ot = 0; ot < 4; ++ot) {
      int o = o0 + 16 * ot + lr;
      wf[ot] = *(const short8v*)(wbf + (size_t)o * 256 + 32 * kc + 8 * lg);
    }
#pragma unroll
    for (int pt = 0; pt < 4; ++pt) {
      int p = P0 + 16 * pt + lr;
      xf[pt] = *(const short8v*)(xtmp + (size_t)p * 256 + 32 * kc + 8 * lg);
    }
#pragma unroll
    for (int ot = 0; ot < 4; ++ot)
#pragma unroll
      for (int pt = 0; pt < 4; ++pt)
        acc[ot][pt] = __builtin_amdgcn_mfma_f32_16x16x32_bf16(wf[ot], xf[pt], acc[ot][pt], 0, 0, 0);
  }

  const int bI = P0 >> 14, pp0 = P0 & 16383;
#pragma unroll
  for (int ot = 0; ot < 4; ++ot) {
#pragma unroll
    for (int r = 0; r < 4; ++r) {
      int o = o0 + 16 * ot + 4 * lg + r;
      float bias = pb[o];
#pragma unroll
      for (int pt = 0; pt < 4; ++pt) {
        int p = pp0 + 16 * pt + lr;
        out[((size_t)(bI * 256 + o)) * PLANE + p] = acc[ot][pt][r] + bias;
      }
    }
  }
}

extern "C" void kernel_launch(void* const* d_in, const int* in_sizes, int n_in,
                              void* d_out, int out_size, void* d_ws, size_t ws_size,
                              hipStream_t stream) {
  const float* qkv  = (const float*)d_in[0];
  const float* ch   = (const float*)d_in[1];
  const float* lsc  = (const float*)d_in[2];
  const float* btab = (const float*)d_in[3];
  const float* pw   = (const float*)d_in[4];
  const float* pb   = (const float*)d_in[5];
  const int*   ridx = (const int*)d_in[6];
  float* out = (float*)d_out;

  char* ws = (char*)d_ws;
  unsigned short* xtmp  = (unsigned short*)ws;                       // 32 MB
  float*          chm   = (float*)(ws + 33554432);                   // 8 MB
  float*          biasG = (float*)(ws + 33554432 + 8388608);         // 128 KB
  unsigned short* wbf   = (unsigned short*)(ws + 33554432 + 8388608 + 131072);

  prep_kernel<<<dim3(8448), dim3(256), 0, stream>>>(ch, btab, ridx, pw,
                                                    chm, biasG, (unsigned int*)wbf);
  attn_kernel<<<dim3(4096), dim3(256), 0, stream>>>(qkv, chm, lsc, biasG, xtmp);
  proj_kernel<<<dim3(1024), dim3(256), 0, stream>>>(xtmp, wbf, pb, out);
}